// Round 4
// baseline (470.270 us; speedup 1.0000x reference)
//
#include <hip/hip_runtime.h>

typedef float v2f __attribute__((ext_vector_type(2)));

#define B_ 64
#define N_ 4096
#define C_ 128
#define W_ 64
#define WIN_ 4033
#define CG 16       // channels per block
#define NCHUNK 64   // n per staged chunk
#define NSPLIT 2    // grid-level split of the n range
#define KPAD 4176   // padded w row: kk = k + 64, k in [-64, 4112)
#define WROW 128    // staged u range per chunk (NCHUNK + 64) = 1024 B per row
#define WSTRIDE 130 // LDS row stride in v2f: even -> 16B-aligned rows (lds-dma), 2-way bank alias (free)
#define LDSBUF (CG * WSTRIDE)  // 2080 v2f per buffer

// Build interleaved, zero-padded weight table w2pad[c][kk] = (wr[c][k], wi[c][k]), k = kk-64
__global__ void prep_w(const float* __restrict__ wr, const float* __restrict__ wi,
                       v2f* __restrict__ w2pad) {
  int idx = blockIdx.x * 256 + threadIdx.x;  // exact: C_*KPAD = 2088*256
  int c = idx / KPAD;
  int kk = idx - c * KPAD;
  int k = kk - 64;
  v2f v = {0.f, 0.f};
  if (k >= 0 && k < WIN_) {
    v.x = wr[c * WIN_ + k];
    v.y = wi[c * WIN_ + k];
  }
  w2pad[idx] = v;
}

// Depthwise sliding correlation (both components packed), pre-nonlinearity partials.
// Grid: 64 b * 8 cgroups * NSPLIT = 1024 blocks, 256 threads (target 4 blocks/CU).
// Thread roles: cl = tid&15 (channel), t0g = (tid>>4)&3 (t-block), np = tid>>6 (16 n each).
// Double-buffered LDS w staging via global_load_lds (1024 B row = one size-16 DMA per row),
// issued one chunk ahead; x prefetched one chunk ahead into ping-pong register arrays.
__global__ __launch_bounds__(256, 3) void conv_main(
    const v2f* __restrict__ x2,     // [B][N][C] float2 (r,i)
    const v2f* __restrict__ w2pad,  // [C][KPAD]
    v2f* __restrict__ fq) {         // [NSPLIT][B][64 t][C] partial filter outputs
  __shared__ __attribute__((aligned(16))) v2f wsh[2 * LDSBUF];  // 33280 B

  int tid = threadIdx.x;
  int bid = blockIdx.x;
  int cg = bid & 7;  // XCD-friendly: each XCD sees one w-slice (L2-resident, 535 KB)
  int bb = (bid >> 3) & 63;
  int ns = bid >> 9;
  int cbase = cg * CG;
  int cl = tid & 15;
  int t0 = ((tid >> 4) & 3) << 4;
  int np = tid >> 6;
  int nbase = np << 4;  // 16 n per wave-partition
  int lane = tid & 63;
  int wv_ = tid >> 6;

  v2f zero = {0.f, 0.f};
  v2f acc[16];
#pragma unroll
  for (int i = 0; i < 16; i++) acc[i] = zero;

  const v2f* xg = x2 + (size_t)bb * N_ * C_ + cbase + cl;
  int nstart = ns * (N_ / NSPLIT);

  // stage chunk starting at global u = n0s into LDS buffer buf (async DMA, no VGPR data).
  // Each wave moves 4 rows; one row = 128 v2f = 1024 B = one size-16 global_load_lds.
  auto stage = [&](int buf, int n0s) {
#pragma unroll
    for (int rr = 0; rr < 4; rr++) {
      int r = wv_ * 4 + rr;
      const char* src =
          (const char*)(w2pad + (size_t)(cbase + r) * KPAD + n0s) + (size_t)lane * 16;
      v2f* dst = wsh + buf * LDSBUF + r * WSTRIDE;  // wave-uniform
      __builtin_amdgcn_global_load_lds(
          (const __attribute__((address_space(1))) unsigned int*)src,
          (__attribute__((address_space(3))) unsigned int*)dst, 16, 0, 0);
    }
  };

  auto loadx = [&](int n0x, v2f* xv) {
#pragma unroll
    for (int j = 0; j < 16; j++) xv[j] = xg[(size_t)(n0x + nbase + j) * C_];
  };

  // one chunk: stage next into buf^1, prefetch next x into xN, compute from buf & xC.
  auto chunk = [&](int buf, const v2f* xC, v2f* xN, int sn0, int xn0) {
    stage(buf ^ 1, sn0);
    const v2f* wrow = wsh + buf * LDSBUF + cl * WSTRIDE;
    v2f wA[16], wB[16];
#pragma unroll
    for (int m = 0; m < 16; m++) wA[m] = wrow[nbase + 48 - t0 + m];
    loadx(xn0, xN);  // prefetch for next chunk (independent of LDS)
#pragma unroll
    for (int j = 0; j < 16; j++) wB[j] = wrow[nbase + 64 - t0 + j];
#pragma unroll
    for (int j = 0; j < 16; j++) {
#pragma unroll
      for (int i = 0; i < 16; i++) {
        int e = j - i;  // w2loc[nbase+64-t0+(j-i)]
        v2f wvv = (e < 0) ? wA[16 + e] : wB[e];
        acc[i] = __builtin_elementwise_fma(xC[j], wvv, acc[i]);
      }
    }
    __syncthreads();  // drains this wave's DMA + x loads; next buffer ready after barrier
  };

  v2f xE[16], xO[16];
  stage(0, nstart);
  loadx(nstart, xE);
  __syncthreads();

  const int WLIM = KPAD - WROW;  // 4048: max valid staging start
  const int XLIM = N_ - NCHUNK;  // 4032: max valid x-chunk start

  for (int k = 0; k < (N_ / NSPLIT) / NCHUNK; k += 2) {  // 32 chunks, 2 per iter
    int n0 = nstart + k * NCHUNK;
    int s1 = n0 + NCHUNK;  // always in-bounds (max 4032 <= WLIM/XLIM)
    chunk(0, xE, xO, s1, s1);
    int s2 = n0 + 2 * NCHUNK;
    int s2w = s2 > WLIM ? WLIM : s2;  // last iter: redundant restage (harmless)
    int s2x = s2 > XLIM ? XLIM : s2;  // last iter: redundant prefetch (harmless)
    chunk(1, xO, xE, s2w, s2x);
  }

  // ---- reduce n-partials across np (2 rounds, half-size LDS), wave 0 writes fq ----
  v2f* fpart = wsh;  // reuse: [2][cl*65 + t], stride 65 (odd) -> conflict-free
  if (np >= 2) {
#pragma unroll
    for (int i = 0; i < 16; i++) fpart[(np - 2) * 1040 + cl * 65 + t0 + i] = acc[i];
  }
  __syncthreads();
  if (np < 2) {
#pragma unroll
    for (int i = 0; i < 16; i++) acc[i] += fpart[np * 1040 + cl * 65 + t0 + i];
  }
  __syncthreads();
  if (np == 1) {
#pragma unroll
    for (int i = 0; i < 16; i++) fpart[cl * 65 + t0 + i] = acc[i];
  }
  __syncthreads();
  if (np == 0) {
    v2f* out = fq + (size_t)(ns * B_ + bb) * 64 * C_ + cbase + cl;
#pragma unroll
    for (int i = 0; i < 16; i++) {
      v2f r = acc[i] + fpart[cl * 65 + t0 + i];
      out[(size_t)(t0 + i) * C_] = r;
    }
  }
}

// Sum the NSPLIT partials, apply per-channel 2x2 + cubic nonlinearity + shared 2x2,
// then the per-channel output filter over t. 64 blocks (b) x 256 threads (c x 2 t-halves).
__global__ void nonlin_out(const v2f* __restrict__ fq, const float* __restrict__ Anl,
                           const float* __restrict__ Wcm, const float* __restrict__ wor,
                           const float* __restrict__ woi, v2f* __restrict__ pre) {
  int b = blockIdx.x;
  int tid = threadIdx.x;
  int c = tid & 127, th = tid >> 7;
  float a00 = Anl[c * 4 + 0], a01 = Anl[c * 4 + 1];
  float a10 = Anl[c * 4 + 2], a11 = Anl[c * 4 + 3];
  float wc00 = Wcm[0], wc01 = Wcm[1], wc10 = Wcm[2], wc11 = Wcm[3];
  const v2f* f0 = fq + (size_t)b * 64 * C_ + c;
  const v2f* f1 = fq + (size_t)(B_ + b) * 64 * C_ + c;
  float or_ = 0.f, oi_ = 0.f;
#pragma unroll 8
  for (int tt = 0; tt < 32; tt++) {
    int t = th * 32 + tt;
    v2f f = f0[(size_t)t * C_] + f1[(size_t)t * C_];
    float ur = a00 * f.x + a01 * f.y;
    float ui = a10 * f.x + a11 * f.y;
    float amp = ur * ur + ui * ui;
    ur *= amp;
    ui *= amp;
    float vr = wc00 * ur + wc01 * ui;
    float vi = wc10 * ur + wc11 * ui;
    or_ += vr * wor[c * 64 + t];
    oi_ += vi * woi[c * 64 + t];
  }
  __shared__ float redr[128], redi[128];
  if (th == 1) {
    redr[c] = or_;
    redi[c] = oi_;
  }
  __syncthreads();
  if (th == 0) {
    v2f r = {or_ + redr[c], oi_ + redi[c]};
    pre[(size_t)b * C_ + c] = r;
  }
}

// Train-mode BatchNorm1d over (B, comp) per channel. 128 blocks (c) x 128 threads.
__global__ void bn_kernel(const float* __restrict__ pre, const float* __restrict__ gamma,
                          const float* __restrict__ beta, float* __restrict__ out) {
  int c = blockIdx.x, tid = threadIdx.x;
  int b = tid >> 1, comp = tid & 1;
  float v = pre[((size_t)b * C_ + c) * 2 + comp];
  float s = v, s2 = v * v;
#pragma unroll
  for (int d = 32; d > 0; d >>= 1) {
    s += __shfl_down(s, d, 64);
    s2 += __shfl_down(s2, d, 64);
  }
  __shared__ float red[4];
  if ((tid & 63) == 0) {
    red[(tid >> 6) * 2 + 0] = s;
    red[(tid >> 6) * 2 + 1] = s2;
  }
  __syncthreads();
  float sum = red[0] + red[2], sumsq = red[1] + red[3];
  float mean = sum * 0.0078125f;
  float var = sumsq * 0.0078125f - mean * mean;
  float inv = rsqrtf(var + 1e-5f);
  out[((size_t)b * C_ + c) * 2 + comp] = (v - mean) * inv * gamma[c] + beta[c];
}

extern "C" void kernel_launch(void* const* d_in, const int* in_sizes, int n_in,
                              void* d_out, int out_size, void* d_ws, size_t ws_size,
                              hipStream_t stream) {
  (void)in_sizes; (void)n_in; (void)out_size; (void)ws_size;
  const float* x   = (const float*)d_in[0];
  const float* wir = (const float*)d_in[1];
  const float* wii = (const float*)d_in[2];
  const float* Anl = (const float*)d_in[3];
  const float* Wcm = (const float*)d_in[4];
  const float* wrr = (const float*)d_in[5];
  const float* wri = (const float*)d_in[6];
  const float* gam = (const float*)d_in[7];
  const float* bet = (const float*)d_in[8];

  v2f* w2pad = (v2f*)d_ws;  // 4.28 MB
  v2f* fq = (v2f*)((char*)d_ws + (size_t)C_ * KPAD * sizeof(v2f));        // 8.39 MB
  v2f* pre = (v2f*)((char*)fq + (size_t)NSPLIT * B_ * 64 * C_ * sizeof(v2f));  // 64 KB

  prep_w<<<(C_ * KPAD) / 256, 256, 0, stream>>>(wir, wii, w2pad);
  conv_main<<<B_ * 8 * NSPLIT, 256, 0, stream>>>((const v2f*)x, w2pad, fq);
  nonlin_out<<<B_, 256, 0, stream>>>(fq, Anl, Wcm, wrr, wri, pre);
  bn_kernel<<<C_, 128, 0, stream>>>((const float*)pre, gam, bet, (float*)d_out);
}

// Round 5
// 447.683 us; speedup vs baseline: 1.0505x; 1.0505x over previous
//
#include <hip/hip_runtime.h>

typedef float v2f __attribute__((ext_vector_type(2)));

#define B_ 64
#define N_ 4096
#define C_ 128
#define W_ 64
#define WIN_ 4033
#define CG 16       // channels per block
#define NCHUNK 64   // n per staged chunk
#define NSPLIT 2    // grid-level split of the n range
#define KPAD 4176   // padded w row: kk = k + 64, k in [-64, 4112)
#define WROW 128    // staged w span per chunk (NCHUNK + 64) = 1024 B per row
#define WSTRIDE 130 // LDS w row stride in v2f: even -> 16B-aligned rows for DMA; 2-way alias is ~free
#define LDSBUF (CG * WSTRIDE)  // 2080 v2f per w buffer
#define XBUF (NCHUNK * CG)     // 1024 v2f per x buffer, layout [n][16 c]

// Build interleaved, zero-padded weight table w2pad[c][kk] = (wr[c][k], wi[c][k]), k = kk-64
__global__ void prep_w(const float* __restrict__ wr, const float* __restrict__ wi,
                       v2f* __restrict__ w2pad) {
  int idx = blockIdx.x * 256 + threadIdx.x;  // exact: C_*KPAD = 2088*256
  int c = idx / KPAD;
  int kk = idx - c * KPAD;
  int k = kk - 64;
  v2f v = {0.f, 0.f};
  if (k >= 0 && k < WIN_) {
    v.x = wr[c * WIN_ + k];
    v.y = wi[c * WIN_ + k];
  }
  w2pad[idx] = v;
}

// Depthwise sliding correlation (both components packed), pre-nonlinearity partials.
// Grid: 64 b * 8 cgroups * NSPLIT = 1024 blocks, 256 threads.
// BOTH w and x are staged via global_load_lds into double-buffered LDS, issued one
// chunk ahead: no VGPR data path for loads -> compiler cannot serialize them
// (round-4 lesson: VGPR_Count=64 proved register-array prefetch gets sunk).
// Thread roles: cl = tid&15 (channel), t0g = (tid>>4)&3 (t-block), np = tid>>6 (16 n each).
__global__ __launch_bounds__(256, 3) void conv_main(
    const v2f* __restrict__ x2,     // [B][N][C] float2 (r,i)
    const v2f* __restrict__ w2pad,  // [C][KPAD]
    v2f* __restrict__ fq) {         // [NSPLIT][B][64 t][C] partial filter outputs
  __shared__ __attribute__((aligned(16))) v2f wsh[2 * LDSBUF];  // 33280 B
  __shared__ __attribute__((aligned(16))) v2f xsh[2 * XBUF];    // 16384 B

  int tid = threadIdx.x;
  int bid = blockIdx.x;
  int cg = bid & 7;  // XCD-friendly: each XCD sees one w-slice (L2-resident, 535 KB)
  int bb = (bid >> 3) & 63;
  int ns = bid >> 9;
  int cbase = cg * CG;
  int cl = tid & 15;
  int t0 = ((tid >> 4) & 3) << 4;
  int np = tid >> 6;
  int nbase = np << 4;  // 16 n per wave-partition
  int lane = tid & 63;
  int wv_ = tid >> 6;

  v2f zero = {0.f, 0.f};
  v2f acc[16];
#pragma unroll
  for (int i = 0; i < 16; i++) acc[i] = zero;

  int nstart = ns * (N_ / NSPLIT);

  // w: each wave DMAs 4 rows; one row = 128 v2f = 1024 B = one size-16 global_load_lds.
  auto stagew = [&](int buf, int n0s) {
#pragma unroll
    for (int rr = 0; rr < 4; rr++) {
      int r = wv_ * 4 + rr;
      const char* src =
          (const char*)(w2pad + (size_t)(cbase + r) * KPAD + n0s) + (size_t)lane * 16;
      v2f* dst = wsh + buf * LDSBUF + r * WSTRIDE;  // wave-uniform
      __builtin_amdgcn_global_load_lds(
          (const __attribute__((address_space(1))) unsigned int*)src,
          (__attribute__((address_space(3))) unsigned int*)dst, 16, 0, 0);
    }
  };

  // x: chunk rows n0x..n0x+64; wave wv stages rows [16wv, 16wv+16) as 2 DMAs of 8 rows.
  // Row n -> xsh[buf][n_local*16 + c_local] (128 B contiguous per row, linear dest).
  auto stagex = [&](int buf, int n0x) {
    const char* xbase =
        (const char*)(x2 + (size_t)bb * N_ * C_ + (size_t)n0x * C_ + cbase);
#pragma unroll
    for (int r = 0; r < 2; r++) {
      const char* src =
          xbase + (size_t)(wv_ * 16 + r * 8 + (lane >> 3)) * (C_ * 8) + (size_t)(lane & 7) * 16;
      v2f* dst = xsh + buf * XBUF + (wv_ * 16 + r * 8) * CG;  // wave-uniform
      __builtin_amdgcn_global_load_lds(
          (const __attribute__((address_space(1))) unsigned int*)src,
          (__attribute__((address_space(3))) unsigned int*)dst, 16, 0, 0);
    }
  };

  const int WLIM = KPAD - WROW;  // 4048: max valid w staging start
  const int XLIM = N_ - NCHUNK;  // 4032: max valid x staging start

  // one chunk: stage next chunk (w+x) into buf^1, compute current from buf.
  auto chunk = [&](int buf, int sn0) {
    int sw = sn0 > WLIM ? WLIM : sn0;  // last iter: redundant restage (harmless)
    int sx = sn0 > XLIM ? XLIM : sn0;
    stagew(buf ^ 1, sw);
    stagex(buf ^ 1, sx);
    const v2f* wrow = wsh + buf * LDSBUF + cl * WSTRIDE;
    const v2f* xrow = xsh + buf * XBUF + cl;
    v2f wA[16], wB[16], xv[16];
#pragma unroll
    for (int m = 0; m < 16; m++) wA[m] = wrow[nbase + 48 - t0 + m];
#pragma unroll
    for (int j = 0; j < 16; j++) xv[j] = xrow[(nbase + j) * CG];
#pragma unroll
    for (int j = 0; j < 16; j++) wB[j] = wrow[nbase + 64 - t0 + j];
#pragma unroll
    for (int j = 0; j < 16; j++) {
#pragma unroll
      for (int i = 0; i < 16; i++) {
        int e = j - i;  // w2loc[nbase+64-t0+(j-i)]
        v2f wvv = (e < 0) ? wA[16 + e] : wB[e];
        acc[i] = __builtin_elementwise_fma(xv[j], wvv, acc[i]);
      }
    }
    __syncthreads();  // drains this wave's DMAs; next buffer guaranteed ready
  };

  stagew(0, nstart);
  stagex(0, nstart);
  __syncthreads();

#pragma unroll 1  // keep the 32-chunk loop rolled: body ~400 instrs, protect I-cache
  for (int k = 0; k < (N_ / NSPLIT) / NCHUNK; k += 2) {  // 32 chunks, 2 per iter
    int n0 = nstart + k * NCHUNK;
    chunk(0, n0 + NCHUNK);
    chunk(1, n0 + 2 * NCHUNK);
  }

  // ---- reduce n-partials across np (2 rounds, half-size LDS), wave 0 writes fq ----
  v2f* fpart = wsh;  // reuse: [2][cl*65 + t], stride 65 (odd) -> conflict-free
  if (np >= 2) {
#pragma unroll
    for (int i = 0; i < 16; i++) fpart[(np - 2) * 1040 + cl * 65 + t0 + i] = acc[i];
  }
  __syncthreads();
  if (np < 2) {
#pragma unroll
    for (int i = 0; i < 16; i++) acc[i] += fpart[np * 1040 + cl * 65 + t0 + i];
  }
  __syncthreads();
  if (np == 1) {
#pragma unroll
    for (int i = 0; i < 16; i++) fpart[cl * 65 + t0 + i] = acc[i];
  }
  __syncthreads();
  if (np == 0) {
    v2f* out = fq + (size_t)(ns * B_ + bb) * 64 * C_ + cbase + cl;
#pragma unroll
    for (int i = 0; i < 16; i++) {
      v2f r = acc[i] + fpart[cl * 65 + t0 + i];
      out[(size_t)(t0 + i) * C_] = r;
    }
  }
}

// Sum the NSPLIT partials, apply per-channel 2x2 + cubic nonlinearity + shared 2x2,
// then the per-channel output filter over t. 64 blocks (b) x 256 threads (c x 2 t-halves).
__global__ void nonlin_out(const v2f* __restrict__ fq, const float* __restrict__ Anl,
                           const float* __restrict__ Wcm, const float* __restrict__ wor,
                           const float* __restrict__ woi, v2f* __restrict__ pre) {
  int b = blockIdx.x;
  int tid = threadIdx.x;
  int c = tid & 127, th = tid >> 7;
  float a00 = Anl[c * 4 + 0], a01 = Anl[c * 4 + 1];
  float a10 = Anl[c * 4 + 2], a11 = Anl[c * 4 + 3];
  float wc00 = Wcm[0], wc01 = Wcm[1], wc10 = Wcm[2], wc11 = Wcm[3];
  const v2f* f0 = fq + (size_t)b * 64 * C_ + c;
  const v2f* f1 = fq + (size_t)(B_ + b) * 64 * C_ + c;
  float or_ = 0.f, oi_ = 0.f;
#pragma unroll 8
  for (int tt = 0; tt < 32; tt++) {
    int t = th * 32 + tt;
    v2f f = f0[(size_t)t * C_] + f1[(size_t)t * C_];
    float ur = a00 * f.x + a01 * f.y;
    float ui = a10 * f.x + a11 * f.y;
    float amp = ur * ur + ui * ui;
    ur *= amp;
    ui *= amp;
    float vr = wc00 * ur + wc01 * ui;
    float vi = wc10 * ur + wc11 * ui;
    or_ += vr * wor[c * 64 + t];
    oi_ += vi * woi[c * 64 + t];
  }
  __shared__ float redr[128], redi[128];
  if (th == 1) {
    redr[c] = or_;
    redi[c] = oi_;
  }
  __syncthreads();
  if (th == 0) {
    v2f r = {or_ + redr[c], oi_ + redi[c]};
    pre[(size_t)b * C_ + c] = r;
  }
}

// Train-mode BatchNorm1d over (B, comp) per channel. 128 blocks (c) x 128 threads.
__global__ void bn_kernel(const float* __restrict__ pre, const float* __restrict__ gamma,
                          const float* __restrict__ beta, float* __restrict__ out) {
  int c = blockIdx.x, tid = threadIdx.x;
  int b = tid >> 1, comp = tid & 1;
  float v = pre[((size_t)b * C_ + c) * 2 + comp];
  float s = v, s2 = v * v;
#pragma unroll
  for (int d = 32; d > 0; d >>= 1) {
    s += __shfl_down(s, d, 64);
    s2 += __shfl_down(s2, d, 64);
  }
  __shared__ float red[4];
  if ((tid & 63) == 0) {
    red[(tid >> 6) * 2 + 0] = s;
    red[(tid >> 6) * 2 + 1] = s2;
  }
  __syncthreads();
  float sum = red[0] + red[2], sumsq = red[1] + red[3];
  float mean = sum * 0.0078125f;
  float var = sumsq * 0.0078125f - mean * mean;
  float inv = rsqrtf(var + 1e-5f);
  out[((size_t)b * C_ + c) * 2 + comp] = (v - mean) * inv * gamma[c] + beta[c];
}

extern "C" void kernel_launch(void* const* d_in, const int* in_sizes, int n_in,
                              void* d_out, int out_size, void* d_ws, size_t ws_size,
                              hipStream_t stream) {
  (void)in_sizes; (void)n_in; (void)out_size; (void)ws_size;
  const float* x   = (const float*)d_in[0];
  const float* wir = (const float*)d_in[1];
  const float* wii = (const float*)d_in[2];
  const float* Anl = (const float*)d_in[3];
  const float* Wcm = (const float*)d_in[4];
  const float* wrr = (const float*)d_in[5];
  const float* wri = (const float*)d_in[6];
  const float* gam = (const float*)d_in[7];
  const float* bet = (const float*)d_in[8];

  v2f* w2pad = (v2f*)d_ws;  // 4.28 MB
  v2f* fq = (v2f*)((char*)d_ws + (size_t)C_ * KPAD * sizeof(v2f));        // 8.39 MB
  v2f* pre = (v2f*)((char*)fq + (size_t)NSPLIT * B_ * 64 * C_ * sizeof(v2f));  // 64 KB

  prep_w<<<(C_ * KPAD) / 256, 256, 0, stream>>>(wir, wii, w2pad);
  conv_main<<<B_ * 8 * NSPLIT, 256, 0, stream>>>((const v2f*)x, w2pad, fq);
  nonlin_out<<<B_, 256, 0, stream>>>(fq, Anl, Wcm, wrr, wri, pre);
  bn_kernel<<<C_, 128, 0, stream>>>((const float*)pre, gam, bet, (float*)d_out);
}